// Round 8
// baseline (383.794 us; speedup 1.0000x reference)
//
#include <hip/hip_runtime.h>
#include <hip/hip_bf16.h>

typedef __hip_bfloat16 bf16;
typedef unsigned int uint32;
typedef __attribute__((ext_vector_type(8))) short short8;
typedef __attribute__((ext_vector_type(4))) float float4v;
typedef __attribute__((ext_vector_type(16))) float float16v;

#define THREADS 1024
#define LDX 520  // sX row stride in bf16 (16B-aligned rows for ds_read_b128)
#define LDE 68   // sE row stride in f32
#define LOG2E 1.44269504088896340736f

__device__ __forceinline__ bf16 f2b(float x) { return __float2bfloat16(x); }
__device__ __forceinline__ uint32 packbf2(float x, float y) {
  union { __hip_bfloat162 b; uint32 u; } cv;
  cv.b = __float22bfloat162_rn(make_float2(x, y));
  return cv.u;
}
__device__ __forceinline__ bf16 f2b1(float x) {
  union { uint32 u; unsigned short s[2]; } cv;
  cv.u = packbf2(x, x);
  union { unsigned short s; bf16 b; } r;
  r.s = cv.s[0];
  return r.b;
}
__device__ __forceinline__ float exp2_hw(float x) {
#if __has_builtin(__builtin_amdgcn_exp2f)
  return __builtin_amdgcn_exp2f(x);
#else
  float r;
  asm("v_exp_f32 %0, %1" : "=v"(r) : "v"(x));
  return r;
#endif
}
__device__ __forceinline__ float rcp_hw(float x) {
#if __has_builtin(__builtin_amdgcn_rcpf)
  return __builtin_amdgcn_rcpf(x);
#else
  float r;
  asm("v_rcp_f32 %0, %1" : "=v"(r) : "v"(x));
  return r;
#endif
}
// lane<32 <-> lane>=32 half exchange; one v_permlane32_swap yields both halves.
__device__ __forceinline__ void lane32_swap(uint32 a, uint32 b, int q,
                                            uint32& lo, uint32& hi) {
#if __has_builtin(__builtin_amdgcn_permlane32_swap)
  auto r = __builtin_amdgcn_permlane32_swap(a, b, false, false);
  lo = r[0];
  hi = r[1];
  (void)q;
#else
  uint32 pa = (uint32)__shfl_xor((int)a, 32, 64);
  uint32 pb = (uint32)__shfl_xor((int)b, 32, 64);
  lo = q ? pb : a;
  hi = q ? b : pa;
#endif
}

// ---- fused prep. Part A (blocks 0..399): W -> 32x32x16 B-frag layout,
// float4 coalesced reads (4 outputs/thread). Part B (blocks 400..663): E
// tiles one WAVE per W-row, coalesced loads + 8-lane shfl reduce, xLOG2E.
__global__ void prep_all(const float* __restrict__ W1, const float* __restrict__ W2,
                         const float* __restrict__ W3,
                         const float* __restrict__ as1, const float* __restrict__ ad1,
                         const float* __restrict__ as2, const float* __restrict__ ad2,
                         const float* __restrict__ as3, const float* __restrict__ ad3,
                         bf16* __restrict__ dst, bf16* __restrict__ dstE) {
  const int b = blockIdx.x;
  const int t = threadIdx.x;
  if (b < 400) {
    int o = (b * 256 + t) * 4;  // segment sizes all %4==0; n%4==0 within rows
    const float* W;
    int Mlog, loc, dbase;
    if (o < 16384) { W = W1; Mlog = 9; loc = o; dbase = 0; }
    else if (o < 278528) { W = W2; Mlog = 9; loc = o - 16384; dbase = 16384; }
    else { W = W3; Mlog = 8; loc = o - 278528; dbase = 278528; }
    float4 v = *(const float4*)(W + loc);
    int M = 1 << Mlog;
    int n = loc & (M - 1), k = loc >> Mlog;
    int kb = k >> 4, q = (k >> 3) & 1, j = k & 7;
    int base = dbase + ((kb * M + n) * 2 + q) * 8 + j;  // n,n+1,n+2,n+3 -> +16 apart
    dst[base] = f2b(v.x);
    dst[base + 16] = f2b(v.y);
    dst[base + 32] = f2b(v.z);
    dst[base + 48] = f2b(v.w);
    return;
  }
  const int kr = (b - 400) * 4 + (t >> 6);
  const int l = t & 63;
  const float *W, *as_, *ad_;
  int M, lk, dbase;
  if (kr < 32)       { W = W1; as_ = as1; ad_ = ad1; M = 512; lk = kr;       dbase = 0; }
  else if (kr < 544) { W = W2; as_ = as2; ad_ = ad2; M = 512; lk = kr - 32;  dbase = 512; }
  else               { W = W3; as_ = as3; ad_ = ad3; M = 256; lk = kr - 544; dbase = 8704; }
  const float* wr = W + (size_t)lk * M;
  float ps = 0.f, pd = 0.f;
  if (M == 512) {
    float4 w0 = *(const float4*)(wr + 8 * l);
    float4 w1 = *(const float4*)(wr + 8 * l + 4);
    float4 s0 = *(const float4*)(as_ + 8 * l);
    float4 s1 = *(const float4*)(as_ + 8 * l + 4);
    float4 d0 = *(const float4*)(ad_ + 8 * l);
    float4 d1 = *(const float4*)(ad_ + 8 * l + 4);
    ps = w0.x * s0.x + w0.y * s0.y + w0.z * s0.z + w0.w * s0.w +
         w1.x * s1.x + w1.y * s1.y + w1.z * s1.z + w1.w * s1.w;
    pd = w0.x * d0.x + w0.y * d0.y + w0.z * d0.z + w0.w * d0.w +
         w1.x * d1.x + w1.y * d1.y + w1.z * d1.z + w1.w * d1.w;
  } else {
    float4 w0 = *(const float4*)(wr + 4 * l);
    float4 s0 = *(const float4*)(as_ + 4 * l);
    float4 d0 = *(const float4*)(ad_ + 4 * l);
    ps = w0.x * s0.x + w0.y * s0.y + w0.z * s0.z + w0.w * s0.w;
    pd = w0.x * d0.x + w0.y * d0.y + w0.z * d0.z + w0.w * d0.w;
  }
#pragma unroll
  for (int m = 1; m < 8; m <<= 1) {
    ps += __shfl_xor(ps, m, 64);
    pd += __shfl_xor(pd, m, 64);
  }
  const int j = lk & 7, kc = (lk >> 3) & 3, ks = lk >> 5;
  const int h = l >> 3;
  const int base = dbase + ks * 512 + kc * 8 + j;
  if ((l & 7) == 0) dstE[base + h * 32] = f2b(ps * LOG2E);
  if ((l & 7) == 1) dstE[base + (8 + h) * 32] = f2b(pd * LOG2E);
}

// ============ phase functions (identical math to the R6/R7 kernel) ============

// E-tile: ls|ld for ALL heads of one graph; waves with hu<4 (16x16x32 path).
template <int K>
__device__ __forceinline__ void phaseE(int lane, int hu, const bf16* __restrict__ WE,
                                       const bf16* sX, float* sE) {
  constexpr int KSE = K / 32;
  const int ln16 = lane & 15, kq16 = lane >> 4;
  if (hu < 4) {
    float4v acce = (float4v)0.f;
    float4v acce2 = (float4v)0.f;
#pragma unroll
    for (int ks = 0; ks < KSE; ks += 2) {
      short8 afrE = *(const short8*)(sX + (hu * 16 + ln16) * LDX + ks * 32 + kq16 * 8);
      short8 efr = *(const short8*)(WE + ks * 512 + ln16 * 32 + kq16 * 8);
      acce = __builtin_amdgcn_mfma_f32_16x16x32_bf16(afrE, efr, acce, 0, 0, 0);
      if constexpr (KSE > 1) {
        short8 afrE2 = *(const short8*)(sX + (hu * 16 + ln16) * LDX + (ks + 1) * 32 + kq16 * 8);
        short8 efr2 = *(const short8*)(WE + (ks + 1) * 512 + ln16 * 32 + kq16 * 8);
        acce2 = __builtin_amdgcn_mfma_f32_16x16x32_bf16(afrE2, efr2, acce2, 0, 0, 0);
      }
    }
    if constexpr (KSE > 1) acce = acce + acce2;
    *(float4v*)(sE + ln16 * LDE + hu * 16 + kq16 * 4) = acce;  // sE[col][node]
  }
}

// phase1: h = x@W, pack to bf16 AND transpose C/D->B-frag (permlane32_swap)
// so PB holds PV-ready B-frags across the next barrier.
template <int K, int M, int C>
__device__ __forceinline__ void phaseP1(int lane, int hu, const bf16* __restrict__ Wswz,
                                        const bf16* sX, uint32 (&PB)[2][4][4]) {
  constexpr int NCT = C / 32, KS16 = K / 16;
  const int c = lane & 31, q = lane >> 5;
  const int colbase = hu * C;
  float16v acc[2][NCT];
#pragma unroll
  for (int rt = 0; rt < 2; ++rt)
#pragma unroll
    for (int ct = 0; ct < NCT; ++ct) acc[rt][ct] = (float16v)0.f;
  const bf16* ap = sX + c * LDX + q * 8;
  const bf16* bp = Wswz + ((colbase + c) * 2 + q) * 8;
#pragma unroll 4
  for (int ks = 0; ks < KS16; ++ks) {
    short8 afr[2];
    afr[0] = *(const short8*)(ap + ks * 16);
    afr[1] = *(const short8*)(ap + 32 * LDX + ks * 16);
    short8 bfr[NCT];
#pragma unroll
    for (int ct = 0; ct < NCT; ++ct)
      bfr[ct] = *(const short8*)(bp + (size_t)ks * (M * 16) + ct * 32 * 16);
#pragma unroll
    for (int rt = 0; rt < 2; ++rt)
#pragma unroll
      for (int ct = 0; ct < NCT; ++ct)
        acc[rt][ct] = __builtin_amdgcn_mfma_f32_32x32x16_bf16(
            afr[rt], bfr[ct], acc[rt][ct], 0, 0, 0);
  }
  // fused pack+transpose; acc dies here. C/D row=(r&3)+8*(r>>2)+4q.
#pragma unroll
  for (int ct = 0; ct < NCT; ++ct)
#pragma unroll
    for (int rt = 0; rt < 2; ++rt)
#pragma unroll
      for (int tp = 0; tp < 2; ++tp) {
        const int tt = rt * 2 + tp;
        uint32 U0 = packbf2(acc[rt][ct][8 * tp + 0], acc[rt][ct][8 * tp + 1]);
        uint32 U1 = packbf2(acc[rt][ct][8 * tp + 2], acc[rt][ct][8 * tp + 3]);
        uint32 V0 = packbf2(acc[rt][ct][8 * tp + 4], acc[rt][ct][8 * tp + 5]);
        uint32 V1 = packbf2(acc[rt][ct][8 * tp + 6], acc[rt][ct][8 * tp + 7]);
        uint32 d0, d1, d2, d3;
        lane32_swap(U0, V0, q, d0, d2);  // d0: own-U/partner-V; d2: partner-U/own-V
        lane32_swap(U1, V1, q, d1, d3);
        PB[ct][tt][0] = d0; PB[ct][tt][1] = d1;
        PB[ct][tt][2] = d2; PB[ct][tt][3] = d3;
      }
}

// softmax + PV + bias + store. Reads sE (published last region) and PB.
template <int C, bool LAST>
__device__ __forceinline__ void phaseSMPV(int lane, int hu, const float* __restrict__ bias,
                                          bf16* sX, const float* sE,
                                          const uint32 (&PB)[2][4][4]) {
  constexpr int NCT = C / 32;
  const int c = lane & 31, q = lane >> 5;
  const int colbase = hu * C;
  const float* lsrow = sE + hu * LDE;
  const float* ldrow = sE + (8 + hu) * LDE;
  short8 pfr[2][4];
#pragma unroll
  for (int rt = 0; rt < 2; ++rt) {
    const float ldi = ldrow[rt * 32 + c];
    float pe_[4][8];
    float rs[4];
#pragma unroll
    for (int tt = 0; tt < 4; ++tt) {
      float4 v0 = *(const float4*)(lsrow + tt * 16 + q * 8);
      float4 v1 = *(const float4*)(lsrow + tt * 16 + q * 8 + 4);
      float ls8[8] = {v0.x, v0.y, v0.z, v0.w, v1.x, v1.y, v1.z, v1.w};
      float s = 0.f;
#pragma unroll
      for (int jj = 0; jj < 8; ++jj) {
        float tv = ldi + ls8[jj];
        float e = exp2_hw(fmaxf(tv, 0.2f * tv));  // inputs pre-scaled by log2e
        pe_[tt][jj] = e;
        s += e;
      }
      rs[tt] = s;
    }
    float rsum = (rs[0] + rs[1]) + (rs[2] + rs[3]);
    rsum += __shfl_xor(rsum, 32, 64);
    const float ri = rcp_hw(rsum);
#pragma unroll
    for (int tt = 0; tt < 4; ++tt) {
      union { uint32 d[4]; short8 s; } w;
#pragma unroll
      for (int jp = 0; jp < 4; ++jp)
        w.d[jp] = packbf2(pe_[tt][2 * jp] * ri, pe_[tt][2 * jp + 1] * ri);
      pfr[rt][tt] = w.s;
    }
  }
#pragma unroll
  for (int ct = 0; ct < NCT; ++ct) {
    float16v oacc[2];
    oacc[0] = (float16v)0.f;
    oacc[1] = (float16v)0.f;
#pragma unroll
    for (int tt = 0; tt < 4; ++tt) {
      union { uint32 d[4]; short8 s; } u;
      u.d[0] = PB[ct][tt][0]; u.d[1] = PB[ct][tt][1];
      u.d[2] = PB[ct][tt][2]; u.d[3] = PB[ct][tt][3];
      oacc[0] = __builtin_amdgcn_mfma_f32_32x32x16_bf16(pfr[0][tt], u.s, oacc[0], 0, 0, 0);
      oacc[1] = __builtin_amdgcn_mfma_f32_32x32x16_bf16(pfr[1][tt], u.s, oacc[1], 0, 0, 0);
    }
    const float bv = bias[colbase + ct * 32 + c];
#pragma unroll
    for (int rt = 0; rt < 2; ++rt)
#pragma unroll
      for (int r = 0; r < 16; ++r) {
        float val = oacc[rt][r] + bv;
        int row = rt * 32 + (r & 3) + 8 * (r >> 2) + 4 * q;
        if constexpr (LAST)
          ((float*)sX)[row * 260 + colbase + ct * 32 + c] = val;
        else
          sX[row * LDX + colbase + ct * 32 + c] = f2b1(val);
      }
  }
}

// ============ two-graph staggered pipeline ============
// 1024 threads = 16 waves; group G = wave>>3 (round-robin wave->SIMD puts
// 2 G0-waves + 2 G1-waves on each SIMD). Schedule (roles; bar after each):
//   r:      0      1      2      3      4      5      6
//   G0:   EP1_1  SMPV1  EP1_2  SMPV2  EP1_3  SMPV3  meanA
//   G1:   idle   EP1_1  SMPV1  EP1_2  SMPV2  EP1_3  SMPV3   (meanB after)
// Every steady region pairs MFMA-heavy (E+P1) of one graph with VALU-heavy
// (SM+PV) of the other on the same SIMDs. Deps cross exactly one barrier.
// LDS 141824 -> 1 block/CU, 16 waves/CU (same as before). PB is the only
// cross-barrier register state (32 VGPR). WRITE_SIZE is the spill tripwire.
__global__ __launch_bounds__(THREADS, 4) void gat3_pipe(
    const float* __restrict__ xs, const float* __restrict__ pe,
    const bf16* __restrict__ W1s, const bf16* __restrict__ WE1,
    const float* __restrict__ b1, const bf16* __restrict__ W2s,
    const bf16* __restrict__ WE2, const float* __restrict__ b2,
    const bf16* __restrict__ W3s, const bf16* __restrict__ WE3,
    const float* __restrict__ b3, float* __restrict__ out) {
  extern __shared__ char smem[];
  bf16* sXA = (bf16*)smem;                       // 66560 B
  bf16* sXB = (bf16*)(smem + 66560);             // 66560 B
  float* sEA = (float*)(smem + 133120);          // 4352 B
  float* sEB = (float*)(smem + 137472);          // 4352 B -> total 141824

  const int t = threadIdx.x;
  const int lane = t & 63;
  const int w = t >> 6;
  const int G = w >> 3;                          // graph group
  const int hu = __builtin_amdgcn_readfirstlane(w & 7);
  const int blk0 = blockIdx.x * 2;               // graphs 2b, 2b+1

  // x0 = concat(xs, broadcast pos_enc) for both graphs
  for (int idx = t; idx < 2 * 64 * 32; idx += THREADS) {
    int g = idx >> 11, loc = idx & 2047;
    int n = loc >> 5, f = loc & 31;
    int blk = blk0 + g;
    float v = (f == 0) ? xs[blk * 64 + n] : pe[((blk >> 8) * 64 + n) * 31 + (f - 1)];
    (g ? sXB : sXA)[n * LDX + f] = f2b(v);
  }
  __syncthreads();

  bf16* sXg = G ? sXB : sXA;
  float* sEg = G ? sEB : sEA;

  uint32 PB[2][4][4];  // packed+transposed h; lives across one barrier
#pragma unroll 1
  for (int r = 0; r < 7; ++r) {
    const int role = r + 1 - G;
    if (role == 1) {
      phaseE<32>(lane, hu, WE1, sXg, sEg);
      phaseP1<32, 512, 64>(lane, hu, W1s, sXg, PB);
    } else if (role == 2) {
      phaseSMPV<64, false>(lane, hu, b1, sXg, sEg, PB);
    } else if (role == 3) {
      phaseE<512>(lane, hu, WE2, sXg, sEg);
      phaseP1<512, 512, 64>(lane, hu, W2s, sXg, PB);
    } else if (role == 4) {
      phaseSMPV<64, false>(lane, hu, b2, sXg, sEg, PB);
    } else if (role == 5) {
      phaseE<512>(lane, hu, WE3, sXg, sEg);
      phaseP1<512, 256, 32>(lane, hu, W3s, sXg, PB);
    } else if (role == 6) {
      phaseSMPV<32, true>(lane, hu, b3, sXg, sEg, PB);
    } else if (role == 7) {
      // drain overlap: mean of graph A (ready since r=5) while G1 runs SMPV3
      if (t < 256) {
        const float* xf = (const float*)sXA;
        float s = 0.f;
#pragma unroll 8
        for (int i = 0; i < 64; ++i) s += xf[i * 260 + t];
        out[blk0 * 256 + t] = s * 0.015625f;
      }
    }
    __syncthreads();
  }

  // mean of graph B
  if (t < 256) {
    const float* xf = (const float*)sXB;
    float s = 0.f;
#pragma unroll 8
    for (int i = 0; i < 64; ++i) s += xf[i * 260 + t];
    out[(blk0 + 1) * 256 + t] = s * 0.015625f;
  }
}

extern "C" void kernel_launch(void* const* d_in, const int* in_sizes, int n_in,
                              void* d_out, int out_size, void* d_ws, size_t ws_size,
                              hipStream_t stream) {
  const float* xs = (const float*)d_in[0];
  const float* pe = (const float*)d_in[1];
  const float* W1 = (const float*)d_in[2];
  const float* as1 = (const float*)d_in[3];
  const float* ad1 = (const float*)d_in[4];
  const float* b1 = (const float*)d_in[5];
  const float* W2 = (const float*)d_in[6];
  const float* as2 = (const float*)d_in[7];
  const float* ad2 = (const float*)d_in[8];
  const float* b2 = (const float*)d_in[9];
  const float* W3 = (const float*)d_in[10];
  const float* as3 = (const float*)d_in[11];
  const float* ad3 = (const float*)d_in[12];
  const float* b3 = (const float*)d_in[13];

  bf16* Wall = (bf16*)d_ws;          // 409600 elems
  bf16* WEall = Wall + 409600;       // 16896 elems
  bf16* W1s = Wall;
  bf16* W2s = Wall + 16384;
  bf16* W3s = Wall + 278528;
  bf16* WE1 = WEall;
  bf16* WE2 = WEall + 512;
  bf16* WE3 = WEall + 8704;

  // parts A (400 blocks, float4) + B (264 blocks) fused
  prep_all<<<dim3(664), dim3(256), 0, stream>>>(
      W1, W2, W3, as1, ad1, as2, ad2, as3, ad3, Wall, WEall);

  static bool smem_inited = false;
  if (!smem_inited) {
    (void)hipFuncSetAttribute((const void*)gat3_pipe,
                              hipFuncAttributeMaxDynamicSharedMemorySize,
                              141824);
    smem_inited = true;
  }
  gat3_pipe<<<dim3(1024), dim3(THREADS), 141824, stream>>>(
      xs, pe, W1s, WE1, b1, W2s, WE2, b2, W3s, WE3, b3, (float*)d_out);
}

// Round 9
// 244.790 us; speedup vs baseline: 1.5679x; 1.5679x over previous
//
#include <hip/hip_runtime.h>
#include <hip/hip_bf16.h>

typedef __hip_bfloat16 bf16;
typedef unsigned int uint32;
typedef __attribute__((ext_vector_type(8))) short short8;
typedef __attribute__((ext_vector_type(4))) float float4v;
typedef __attribute__((ext_vector_type(16))) float float16v;

#define THREADS 1024
#define LDX 520  // sX row stride in bf16 (16B-aligned rows for ds_read_b128)
#define LDE 68   // sE row stride in f32
#define LOG2E 1.44269504088896340736f

__device__ __forceinline__ bf16 f2b(float x) { return __float2bfloat16(x); }
__device__ __forceinline__ uint32 packbf2(float x, float y) {
  union { __hip_bfloat162 b; uint32 u; } cv;
  cv.b = __float22bfloat162_rn(make_float2(x, y));
  return cv.u;
}
__device__ __forceinline__ bf16 f2b1(float x) {
  union { uint32 u; unsigned short s[2]; } cv;
  cv.u = packbf2(x, x);
  union { unsigned short s; bf16 b; } r;
  r.s = cv.s[0];
  return r.b;
}
__device__ __forceinline__ float exp2_hw(float x) {
#if __has_builtin(__builtin_amdgcn_exp2f)
  return __builtin_amdgcn_exp2f(x);
#else
  float r;
  asm("v_exp_f32 %0, %1" : "=v"(r) : "v"(x));
  return r;
#endif
}
__device__ __forceinline__ float rcp_hw(float x) {
#if __has_builtin(__builtin_amdgcn_rcpf)
  return __builtin_amdgcn_rcpf(x);
#else
  float r;
  asm("v_rcp_f32 %0, %1" : "=v"(r) : "v"(x));
  return r;
#endif
}
// lane<32 <-> lane>=32 half exchange; one v_permlane32_swap yields both halves.
__device__ __forceinline__ void lane32_swap(uint32 a, uint32 b, int q,
                                            uint32& lo, uint32& hi) {
#if __has_builtin(__builtin_amdgcn_permlane32_swap)
  auto r = __builtin_amdgcn_permlane32_swap(a, b, false, false);
  lo = r[0];
  hi = r[1];
  (void)q;
#else
  uint32 pa = (uint32)__shfl_xor((int)a, 32, 64);
  uint32 pb = (uint32)__shfl_xor((int)b, 32, 64);
  lo = q ? pb : a;
  hi = q ? b : pa;
#endif
}

// ---- fused prep. Part A (blocks 0..399): W -> 32x32x16 B-frag layout,
// float4 coalesced reads (4 outputs/thread). Part B (blocks 400..663): E
// tiles one WAVE per W-row, coalesced loads + 8-lane shfl reduce, xLOG2E.
__global__ void prep_all(const float* __restrict__ W1, const float* __restrict__ W2,
                         const float* __restrict__ W3,
                         const float* __restrict__ as1, const float* __restrict__ ad1,
                         const float* __restrict__ as2, const float* __restrict__ ad2,
                         const float* __restrict__ as3, const float* __restrict__ ad3,
                         bf16* __restrict__ dst, bf16* __restrict__ dstE) {
  const int b = blockIdx.x;
  const int t = threadIdx.x;
  if (b < 400) {
    int o = (b * 256 + t) * 4;  // segment sizes all %4==0; n%4==0 within rows
    const float* W;
    int Mlog, loc, dbase;
    if (o < 16384) { W = W1; Mlog = 9; loc = o; dbase = 0; }
    else if (o < 278528) { W = W2; Mlog = 9; loc = o - 16384; dbase = 16384; }
    else { W = W3; Mlog = 8; loc = o - 278528; dbase = 278528; }
    float4 v = *(const float4*)(W + loc);
    int M = 1 << Mlog;
    int n = loc & (M - 1), k = loc >> Mlog;
    int kb = k >> 4, q = (k >> 3) & 1, j = k & 7;
    int base = dbase + ((kb * M + n) * 2 + q) * 8 + j;  // n..n+3 -> +16 apart
    dst[base] = f2b(v.x);
    dst[base + 16] = f2b(v.y);
    dst[base + 32] = f2b(v.z);
    dst[base + 48] = f2b(v.w);
    return;
  }
  const int kr = (b - 400) * 4 + (t >> 6);
  const int l = t & 63;
  const float *W, *as_, *ad_;
  int M, lk, dbase;
  if (kr < 32)       { W = W1; as_ = as1; ad_ = ad1; M = 512; lk = kr;       dbase = 0; }
  else if (kr < 544) { W = W2; as_ = as2; ad_ = ad2; M = 512; lk = kr - 32;  dbase = 512; }
  else               { W = W3; as_ = as3; ad_ = ad3; M = 256; lk = kr - 544; dbase = 8704; }
  const float* wr = W + (size_t)lk * M;
  float ps = 0.f, pd = 0.f;
  if (M == 512) {
    float4 w0 = *(const float4*)(wr + 8 * l);
    float4 w1 = *(const float4*)(wr + 8 * l + 4);
    float4 s0 = *(const float4*)(as_ + 8 * l);
    float4 s1 = *(const float4*)(as_ + 8 * l + 4);
    float4 d0 = *(const float4*)(ad_ + 8 * l);
    float4 d1 = *(const float4*)(ad_ + 8 * l + 4);
    ps = w0.x * s0.x + w0.y * s0.y + w0.z * s0.z + w0.w * s0.w +
         w1.x * s1.x + w1.y * s1.y + w1.z * s1.z + w1.w * s1.w;
    pd = w0.x * d0.x + w0.y * d0.y + w0.z * d0.z + w0.w * d0.w +
         w1.x * d1.x + w1.y * d1.y + w1.z * d1.z + w1.w * d1.w;
  } else {
    float4 w0 = *(const float4*)(wr + 4 * l);
    float4 s0 = *(const float4*)(as_ + 4 * l);
    float4 d0 = *(const float4*)(ad_ + 4 * l);
    ps = w0.x * s0.x + w0.y * s0.y + w0.z * s0.z + w0.w * s0.w;
    pd = w0.x * d0.x + w0.y * d0.y + w0.z * d0.z + w0.w * d0.w;
  }
#pragma unroll
  for (int m = 1; m < 8; m <<= 1) {
    ps += __shfl_xor(ps, m, 64);
    pd += __shfl_xor(pd, m, 64);
  }
  const int j = lk & 7, kc = (lk >> 3) & 3, ks = lk >> 5;
  const int h = l >> 3;
  const int base = dbase + ks * 512 + kc * 8 + j;
  if ((l & 7) == 0) dstE[base + h * 32] = f2b(ps * LOG2E);
  if ((l & 7) == 1) dstE[base + (8 + h) * 32] = f2b(pd * LOG2E);
}

// ============ phase functions (math validated: R8 passed with these) ============

template <int K>
__device__ __forceinline__ void phaseE(int lane, int hu, const bf16* __restrict__ WE,
                                       const bf16* sX, float* sE) {
  constexpr int KSE = K / 32;
  const int ln16 = lane & 15, kq16 = lane >> 4;
  if (hu < 4) {
    float4v acce = (float4v)0.f;
    float4v acce2 = (float4v)0.f;
#pragma unroll
    for (int ks = 0; ks < KSE; ks += 2) {
      short8 afrE = *(const short8*)(sX + (hu * 16 + ln16) * LDX + ks * 32 + kq16 * 8);
      short8 efr = *(const short8*)(WE + ks * 512 + ln16 * 32 + kq16 * 8);
      acce = __builtin_amdgcn_mfma_f32_16x16x32_bf16(afrE, efr, acce, 0, 0, 0);
      if constexpr (KSE > 1) {
        short8 afrE2 = *(const short8*)(sX + (hu * 16 + ln16) * LDX + (ks + 1) * 32 + kq16 * 8);
        short8 efr2 = *(const short8*)(WE + (ks + 1) * 512 + ln16 * 32 + kq16 * 8);
        acce2 = __builtin_amdgcn_mfma_f32_16x16x32_bf16(afrE2, efr2, acce2, 0, 0, 0);
      }
    }
    if constexpr (KSE > 1) acce = acce + acce2;
    *(float4v*)(sE + ln16 * LDE + hu * 16 + kq16 * 4) = acce;  // sE[col][node]
  }
}

// phase1: h = x@W, fused pack-to-bf16 + C/D->B-frag transpose (permlane32_swap).
// PB holds PV-ready B-frags across exactly ONE barrier.
template <int K, int M, int C>
__device__ __forceinline__ void phaseP1(int lane, int hu, const bf16* __restrict__ Wswz,
                                        const bf16* sX, uint32 (&PB)[2][4][4]) {
  constexpr int NCT = C / 32, KS16 = K / 16;
  const int c = lane & 31, q = lane >> 5;
  const int colbase = hu * C;
  float16v acc[2][NCT];
#pragma unroll
  for (int rt = 0; rt < 2; ++rt)
#pragma unroll
    for (int ct = 0; ct < NCT; ++ct) acc[rt][ct] = (float16v)0.f;
  const bf16* ap = sX + c * LDX + q * 8;
  const bf16* bp = Wswz + ((colbase + c) * 2 + q) * 8;
#pragma unroll 4
  for (int ks = 0; ks < KS16; ++ks) {
    short8 afr[2];
    afr[0] = *(const short8*)(ap + ks * 16);
    afr[1] = *(const short8*)(ap + 32 * LDX + ks * 16);
    short8 bfr[NCT];
#pragma unroll
    for (int ct = 0; ct < NCT; ++ct)
      bfr[ct] = *(const short8*)(bp + (size_t)ks * (M * 16) + ct * 32 * 16);
#pragma unroll
    for (int rt = 0; rt < 2; ++rt)
#pragma unroll
      for (int ct = 0; ct < NCT; ++ct)
        acc[rt][ct] = __builtin_amdgcn_mfma_f32_32x32x16_bf16(
            afr[rt], bfr[ct], acc[rt][ct], 0, 0, 0);
  }
  // fused pack+transpose; acc dies here. C/D row=(r&3)+8*(r>>2)+4q.
#pragma unroll
  for (int ct = 0; ct < NCT; ++ct)
#pragma unroll
    for (int rt = 0; rt < 2; ++rt)
#pragma unroll
      for (int tp = 0; tp < 2; ++tp) {
        const int tt = rt * 2 + tp;
        uint32 U0 = packbf2(acc[rt][ct][8 * tp + 0], acc[rt][ct][8 * tp + 1]);
        uint32 U1 = packbf2(acc[rt][ct][8 * tp + 2], acc[rt][ct][8 * tp + 3]);
        uint32 V0 = packbf2(acc[rt][ct][8 * tp + 4], acc[rt][ct][8 * tp + 5]);
        uint32 V1 = packbf2(acc[rt][ct][8 * tp + 6], acc[rt][ct][8 * tp + 7]);
        uint32 d0, d1, d2, d3;
        lane32_swap(U0, V0, q, d0, d2);
        lane32_swap(U1, V1, q, d1, d3);
        PB[ct][tt][0] = d0; PB[ct][tt][1] = d1;
        PB[ct][tt][2] = d2; PB[ct][tt][3] = d3;
      }
}

// softmax + PV + bias + store. Reads sE (published one barrier ago) and PB.
template <int C, bool LAST>
__device__ __forceinline__ void phaseSMPV(int lane, int hu, const float* __restrict__ bias,
                                          bf16* sX, const float* sE,
                                          const uint32 (&PB)[2][4][4]) {
  constexpr int NCT = C / 32;
  const int c = lane & 31, q = lane >> 5;
  const int colbase = hu * C;
  const float* lsrow = sE + hu * LDE;
  const float* ldrow = sE + (8 + hu) * LDE;
  short8 pfr[2][4];
#pragma unroll
  for (int rt = 0; rt < 2; ++rt) {
    const float ldi = ldrow[rt * 32 + c];
    float pe_[4][8];
    float rs[4];
#pragma unroll
    for (int tt = 0; tt < 4; ++tt) {
      float4 v0 = *(const float4*)(lsrow + tt * 16 + q * 8);
      float4 v1 = *(const float4*)(lsrow + tt * 16 + q * 8 + 4);
      float ls8[8] = {v0.x, v0.y, v0.z, v0.w, v1.x, v1.y, v1.z, v1.w};
      float s = 0.f;
#pragma unroll
      for (int jj = 0; jj < 8; ++jj) {
        float tv = ldi + ls8[jj];
        float e = exp2_hw(fmaxf(tv, 0.2f * tv));  // inputs pre-scaled by log2e
        pe_[tt][jj] = e;
        s += e;
      }
      rs[tt] = s;
    }
    float rsum = (rs[0] + rs[1]) + (rs[2] + rs[3]);
    rsum += __shfl_xor(rsum, 32, 64);
    const float ri = rcp_hw(rsum);
#pragma unroll
    for (int tt = 0; tt < 4; ++tt) {
      union { uint32 d[4]; short8 s; } w;
#pragma unroll
      for (int jp = 0; jp < 4; ++jp)
        w.d[jp] = packbf2(pe_[tt][2 * jp] * ri, pe_[tt][2 * jp + 1] * ri);
      pfr[rt][tt] = w.s;
    }
  }
#pragma unroll
  for (int ct = 0; ct < NCT; ++ct) {
    float16v oacc[2];
    oacc[0] = (float16v)0.f;
    oacc[1] = (float16v)0.f;
#pragma unroll
    for (int tt = 0; tt < 4; ++tt) {
      union { uint32 d[4]; short8 s; } u;
      u.d[0] = PB[ct][tt][0]; u.d[1] = PB[ct][tt][1];
      u.d[2] = PB[ct][tt][2]; u.d[3] = PB[ct][tt][3];
      oacc[0] = __builtin_amdgcn_mfma_f32_32x32x16_bf16(pfr[0][tt], u.s, oacc[0], 0, 0, 0);
      oacc[1] = __builtin_amdgcn_mfma_f32_32x32x16_bf16(pfr[1][tt], u.s, oacc[1], 0, 0, 0);
    }
    const float bv = bias[colbase + ct * 32 + c];
#pragma unroll
    for (int rt = 0; rt < 2; ++rt)
#pragma unroll
      for (int r = 0; r < 16; ++r) {
        float val = oacc[rt][r] + bv;
        int row = rt * 32 + (r & 3) + 8 * (r >> 2) + 4 * q;
        if constexpr (LAST)
          ((float*)sX)[row * 260 + colbase + ct * 32 + c] = val;
        else
          sX[row * LDX + colbase + ct * 32 + c] = f2b1(val);
      }
  }
}

// ============ two-graph staggered pipeline, STATICALLY UNROLLED ============
// R8 lesson: the runtime-role loop made PB live around the backedge -> 142
// B/thread spill (WRITE 2->297 MB). Static regions restore R6's liveness:
// PB lives {EP1(r) -> SMPV(r+1)}, one barrier, peak = max(arm peaks) ~124 regs.
// Schedule (bar after each region):
//   region:  1      2      3      4      5      6      7     tail
//   G0:    EP1_1  SMPV1  EP1_2  SMPV2  EP1_3  SMPV3  meanA
//   G1:     ---   EP1_1  SMPV1  EP1_2  SMPV2  EP1_3  SMPV3  meanB
// Steady regions pair MFMA-heavy (E+P1) with VALU-heavy (SM+PV) on the same
// SIMDs (wave->SIMD round-robin: 2 G0-waves + 2 G1-waves per SIMD).
__global__ __launch_bounds__(THREADS, 4) void gat3_pipe(
    const float* __restrict__ xs, const float* __restrict__ pe,
    const bf16* __restrict__ W1s, const bf16* __restrict__ WE1,
    const float* __restrict__ b1, const bf16* __restrict__ W2s,
    const bf16* __restrict__ WE2, const float* __restrict__ b2,
    const bf16* __restrict__ W3s, const bf16* __restrict__ WE3,
    const float* __restrict__ b3, float* __restrict__ out) {
  extern __shared__ char smem[];
  bf16* sXA = (bf16*)smem;                       // 66560 B
  bf16* sXB = (bf16*)(smem + 66560);             // 66560 B
  float* sEA = (float*)(smem + 133120);          // 4352 B
  float* sEB = (float*)(smem + 137472);          // 4352 B -> total 141824

  const int t = threadIdx.x;
  const int lane = t & 63;
  const int w = t >> 6;
  const int G = __builtin_amdgcn_readfirstlane(w >> 3);   // graph group
  const int hu = __builtin_amdgcn_readfirstlane(w & 7);   // head id
  const int blk0 = blockIdx.x * 2;               // graphs 2b, 2b+1

  // x0 = concat(xs, broadcast pos_enc) for both graphs
  for (int idx = t; idx < 2 * 64 * 32; idx += THREADS) {
    int g = idx >> 11, loc = idx & 2047;
    int n = loc >> 5, f = loc & 31;
    int blk = blk0 + g;
    float v = (f == 0) ? xs[blk * 64 + n] : pe[((blk >> 8) * 64 + n) * 31 + (f - 1)];
    (g ? sXB : sXA)[n * LDX + f] = f2b(v);
  }
  __syncthreads();

  uint32 PB[2][4][4];  // packed+transposed h; lives across exactly one barrier

  // region 1
  if (G == 0) {
    phaseE<32>(lane, hu, WE1, sXA, sEA);
    phaseP1<32, 512, 64>(lane, hu, W1s, sXA, PB);
  }
  __syncthreads();
  // region 2
  if (G == 0) {
    phaseSMPV<64, false>(lane, hu, b1, sXA, sEA, PB);
  } else {
    phaseE<32>(lane, hu, WE1, sXB, sEB);
    phaseP1<32, 512, 64>(lane, hu, W1s, sXB, PB);
  }
  __syncthreads();
  // region 3
  if (G == 0) {
    phaseE<512>(lane, hu, WE2, sXA, sEA);
    phaseP1<512, 512, 64>(lane, hu, W2s, sXA, PB);
  } else {
    phaseSMPV<64, false>(lane, hu, b1, sXB, sEB, PB);
  }
  __syncthreads();
  // region 4
  if (G == 0) {
    phaseSMPV<64, false>(lane, hu, b2, sXA, sEA, PB);
  } else {
    phaseE<512>(lane, hu, WE2, sXB, sEB);
    phaseP1<512, 512, 64>(lane, hu, W2s, sXB, PB);
  }
  __syncthreads();
  // region 5
  if (G == 0) {
    phaseE<512>(lane, hu, WE3, sXA, sEA);
    phaseP1<512, 256, 32>(lane, hu, W3s, sXA, PB);
  } else {
    phaseSMPV<64, false>(lane, hu, b2, sXB, sEB, PB);
  }
  __syncthreads();
  // region 6
  if (G == 0) {
    phaseSMPV<32, true>(lane, hu, b3, sXA, sEA, PB);
  } else {
    phaseE<512>(lane, hu, WE3, sXB, sEB);
    phaseP1<512, 256, 32>(lane, hu, W3s, sXB, PB);
  }
  __syncthreads();
  // region 7
  if (G == 0) {
    if (t < 256) {  // waves 0-3: mean of graph A (final sXA crossed the bar)
      const float* xf = (const float*)sXA;
      float s = 0.f;
#pragma unroll 8
      for (int i = 0; i < 64; ++i) s += xf[i * 260 + t];
      out[blk0 * 256 + t] = s * 0.015625f;
    }
  } else {
    phaseSMPV<32, true>(lane, hu, b3, sXB, sEB, PB);
  }
  __syncthreads();
  // tail: mean of graph B
  if (t < 256) {
    const float* xf = (const float*)sXB;
    float s = 0.f;
#pragma unroll 8
    for (int i = 0; i < 64; ++i) s += xf[i * 260 + t];
    out[(blk0 + 1) * 256 + t] = s * 0.015625f;
  }
}

extern "C" void kernel_launch(void* const* d_in, const int* in_sizes, int n_in,
                              void* d_out, int out_size, void* d_ws, size_t ws_size,
                              hipStream_t stream) {
  const float* xs = (const float*)d_in[0];
  const float* pe = (const float*)d_in[1];
  const float* W1 = (const float*)d_in[2];
  const float* as1 = (const float*)d_in[3];
  const float* ad1 = (const float*)d_in[4];
  const float* b1 = (const float*)d_in[5];
  const float* W2 = (const float*)d_in[6];
  const float* as2 = (const float*)d_in[7];
  const float* ad2 = (const float*)d_in[8];
  const float* b2 = (const float*)d_in[9];
  const float* W3 = (const float*)d_in[10];
  const float* as3 = (const float*)d_in[11];
  const float* ad3 = (const float*)d_in[12];
  const float* b3 = (const float*)d_in[13];

  bf16* Wall = (bf16*)d_ws;          // 409600 elems
  bf16* WEall = Wall + 409600;       // 16896 elems
  bf16* W1s = Wall;
  bf16* W2s = Wall + 16384;
  bf16* W3s = Wall + 278528;
  bf16* WE1 = WEall;
  bf16* WE2 = WEall + 512;
  bf16* WE3 = WEall + 8704;

  prep_all<<<dim3(664), dim3(256), 0, stream>>>(
      W1, W2, W3, as1, ad1, as2, ad2, as3, ad3, Wall, WEall);

  static bool smem_inited = false;
  if (!smem_inited) {
    (void)hipFuncSetAttribute((const void*)gat3_pipe,
                              hipFuncAttributeMaxDynamicSharedMemorySize,
                              141824);
    smem_inited = true;
  }
  gat3_pipe<<<dim3(1024), dim3(THREADS), 141824, stream>>>(
      xs, pe, W1s, WE1, b1, W2s, WE2, b2, W3s, WE3, b3, (float*)d_out);
}

// Round 10
// 232.672 us; speedup vs baseline: 1.6495x; 1.0521x over previous
//
#include <hip/hip_runtime.h>
#include <hip/hip_bf16.h>

typedef __hip_bfloat16 bf16;
typedef unsigned int uint32;
typedef __attribute__((ext_vector_type(8))) short short8;
typedef __attribute__((ext_vector_type(4))) float float4v;
typedef __attribute__((ext_vector_type(16))) float float16v;

#define THREADS 512
#define LDX 520  // sX row stride in bf16 (16B-aligned rows for ds_read_b128)
#define LDE 68   // sE row stride in f32
#define LOG2E 1.44269504088896340736f

__device__ __forceinline__ bf16 f2b(float x) { return __float2bfloat16(x); }
__device__ __forceinline__ uint32 packbf2(float x, float y) {
  union { __hip_bfloat162 b; uint32 u; } cv;
  cv.b = __float22bfloat162_rn(make_float2(x, y));
  return cv.u;
}
// single f32->bf16 via the packed HW convert (1 op), RNE
__device__ __forceinline__ bf16 f2b1(float x) {
  union { uint32 u; unsigned short s[2]; } cv;
  cv.u = packbf2(x, x);
  union { unsigned short s; bf16 b; } r;
  r.s = cv.s[0];
  return r.b;
}
// 2^x via v_exp_f32 (logits are pre-scaled by log2e at prep time)
__device__ __forceinline__ float exp2_hw(float x) {
#if __has_builtin(__builtin_amdgcn_exp2f)
  return __builtin_amdgcn_exp2f(x);
#else
  float r;
  asm("v_exp_f32 %0, %1" : "=v"(r) : "v"(x));
  return r;
#endif
}
__device__ __forceinline__ float rcp_hw(float x) {
#if __has_builtin(__builtin_amdgcn_rcpf)
  return __builtin_amdgcn_rcpf(x);
#else
  float r;
  asm("v_rcp_f32 %0, %1" : "=v"(r) : "v"(x));
  return r;
#endif
}
// lane<32 <-> lane>=32 half exchange; one v_permlane32_swap yields both halves.
__device__ __forceinline__ void lane32_swap(uint32 a, uint32 b, int q,
                                            uint32& lo, uint32& hi) {
#if __has_builtin(__builtin_amdgcn_permlane32_swap)
  auto r = __builtin_amdgcn_permlane32_swap(a, b, false, false);
  lo = r[0];
  hi = r[1];
  (void)q;
#else
  uint32 pa = (uint32)__shfl_xor((int)a, 32, 64);
  uint32 pb = (uint32)__shfl_xor((int)b, 32, 64);
  lo = q ? pb : a;
  hi = q ? b : pa;
#endif
}

// ---- fused prep. Part A (blocks 0..399): W -> 32x32x16 B-frag layout,
// float4 coalesced reads (4 outputs/thread; validated R8/R9). Part B (blocks
// 400..663): E tiles one WAVE per W-row, coalesced loads + 8-lane shfl
// reduce, scaled by log2e (softmax then uses raw v_exp_f32).
__global__ void prep_all(const float* __restrict__ W1, const float* __restrict__ W2,
                         const float* __restrict__ W3,
                         const float* __restrict__ as1, const float* __restrict__ ad1,
                         const float* __restrict__ as2, const float* __restrict__ ad2,
                         const float* __restrict__ as3, const float* __restrict__ ad3,
                         bf16* __restrict__ dst, bf16* __restrict__ dstE) {
  const int b = blockIdx.x;
  const int t = threadIdx.x;
  if (b < 400) {
    int o = (b * 256 + t) * 4;  // segment sizes all %4==0; n%4==0 within rows
    const float* W;
    int Mlog, loc, dbase;
    if (o < 16384) { W = W1; Mlog = 9; loc = o; dbase = 0; }
    else if (o < 278528) { W = W2; Mlog = 9; loc = o - 16384; dbase = 16384; }
    else { W = W3; Mlog = 8; loc = o - 278528; dbase = 278528; }
    float4 v = *(const float4*)(W + loc);
    int M = 1 << Mlog;
    int n = loc & (M - 1), k = loc >> Mlog;
    int kb = k >> 4, q = (k >> 3) & 1, j = k & 7;
    int base = dbase + ((kb * M + n) * 2 + q) * 8 + j;  // n..n+3 -> +16 apart
    dst[base] = f2b(v.x);
    dst[base + 16] = f2b(v.y);
    dst[base + 32] = f2b(v.z);
    dst[base + 48] = f2b(v.w);
    return;
  }
  const int kr = (b - 400) * 4 + (t >> 6);
  const int l = t & 63;
  const float *W, *as_, *ad_;
  int M, lk, dbase;
  if (kr < 32)       { W = W1; as_ = as1; ad_ = ad1; M = 512; lk = kr;       dbase = 0; }
  else if (kr < 544) { W = W2; as_ = as2; ad_ = ad2; M = 512; lk = kr - 32;  dbase = 512; }
  else               { W = W3; as_ = as3; ad_ = ad3; M = 256; lk = kr - 544; dbase = 8704; }
  const float* wr = W + (size_t)lk * M;
  float ps = 0.f, pd = 0.f;
  if (M == 512) {
    float4 w0 = *(const float4*)(wr + 8 * l);
    float4 w1 = *(const float4*)(wr + 8 * l + 4);
    float4 s0 = *(const float4*)(as_ + 8 * l);
    float4 s1 = *(const float4*)(as_ + 8 * l + 4);
    float4 d0 = *(const float4*)(ad_ + 8 * l);
    float4 d1 = *(const float4*)(ad_ + 8 * l + 4);
    ps = w0.x * s0.x + w0.y * s0.y + w0.z * s0.z + w0.w * s0.w +
         w1.x * s1.x + w1.y * s1.y + w1.z * s1.z + w1.w * s1.w;
    pd = w0.x * d0.x + w0.y * d0.y + w0.z * d0.z + w0.w * d0.w +
         w1.x * d1.x + w1.y * d1.y + w1.z * d1.z + w1.w * d1.w;
  } else {
    float4 w0 = *(const float4*)(wr + 4 * l);
    float4 s0 = *(const float4*)(as_ + 4 * l);
    float4 d0 = *(const float4*)(ad_ + 4 * l);
    ps = w0.x * s0.x + w0.y * s0.y + w0.z * s0.z + w0.w * s0.w;
    pd = w0.x * d0.x + w0.y * d0.y + w0.z * d0.z + w0.w * d0.w;
  }
#pragma unroll
  for (int m = 1; m < 8; m <<= 1) {
    ps += __shfl_xor(ps, m, 64);
    pd += __shfl_xor(pd, m, 64);
  }
  const int j = lk & 7, kc = (lk >> 3) & 3, ks = lk >> 5;
  const int h = l >> 3;
  const int base = dbase + ks * 512 + kc * 8 + j;
  if ((l & 7) == 0) dstE[base + h * 32] = f2b(ps * LOG2E);
  if ((l & 7) == 1) dstE[base + (8 + h) * 32] = f2b(pd * LOG2E);
}

// One GAT layer on 32x32x16 MFMA. Wave w == head w (owns C output cols).
// BARRIER STRUCTURE (R6, best measured): E -> bar1 (publish sE) -> [phase1 +
// pack + softmax, UNFENCED so softmax VALU hides under the phase1 MFMA/ds
// stream] -> bar2 (all sX reads done) -> [transpose + PV + store] -> bar3.
// R10: bias folded into the PV accumulator init (C/D elements of a lane all
// share column c, so splat(bias[col]) is exact; bias==0 in this problem ->
// bit-identical).
// REGISTER DISCIPLINE (R2/R3/R8 lessons): __launch_bounds__(512,4) caps the
// unified VGPR+AGPR file at 128/wave; phase 1 holds 64 AGPR of accumulators.
// pe_ array + IMMEDIATE softmax normalization, oacc scoped per-ct: ~124 regs,
// zero spill. Deferred normalization / loop-carried frag state spills ~120+
// B/thread (WRITE_SIZE 2 MB -> 122-297 MB). WRITE_SIZE is the spill tripwire.
// NO setprio (R5: −5% in this lockstep structure, m190). NO forced two-graph
// pairing (R9: barriers couple 16 waves into a convoy, −6% vs free-drifting
// 2-block overlap).
template <int K, int M, int C, bool LAST>
__device__ __forceinline__ void gat_layer(
    int t, const bf16* __restrict__ Wswz, const bf16* __restrict__ WE,
    const float* __restrict__ bias, bf16* sX, float* sE) {
  constexpr int NCT = C / 32;   // 32-col tiles per wave (2 or 1)
  constexpr int KS16 = K / 16;  // 32x32x16 k-steps
  constexpr int KSE = K / 32;   // 16x16x32 k-steps for E
  const int lane = t & 63;
  const int hu = __builtin_amdgcn_readfirstlane(t >> 6);  // wave/head id
  const int c = lane & 31, q = lane >> 5;
  const int ln16 = lane & 15, kq16 = lane >> 4;
  const int colbase = hu * C;

  // ---- E-tile (ls|ld for ALL heads), waves 0-3, 16x16x32 path ----
  if (hu < 4) {
    float4v acce = (float4v)0.f;
#pragma unroll
    for (int ks = 0; ks < KSE; ++ks) {
      short8 afrE = *(const short8*)(sX + (hu * 16 + ln16) * LDX + ks * 32 + kq16 * 8);
      short8 efr = *(const short8*)(WE + ks * 512 + ln16 * 32 + kq16 * 8);
      acce = __builtin_amdgcn_mfma_f32_16x16x32_bf16(afrE, efr, acce, 0, 0, 0);
    }
    // C/D: col=ln16 (as/ad idx), row=kq16*4+r (local node) -> sE[col][node]
    *(float4v*)(sE + ln16 * LDE + hu * 16 + kq16 * 4) = acce;
  }
  __syncthreads();  // bar1: sE visible to all waves; sX untouched so far

  // ---- phase 1: h = x@W (32x32x16), single pass, 2rt x NCT acc chains ----
  uint32 Ppk[NCT][4][4];  // [ct][kstep t][U0,U1,V0,V1] packed bf16x2
  {
    float16v acc[2][NCT];
#pragma unroll
    for (int rt = 0; rt < 2; ++rt)
#pragma unroll
      for (int ct = 0; ct < NCT; ++ct) acc[rt][ct] = (float16v)0.f;
    const bf16* ap = sX + c * LDX + q * 8;
    const bf16* bp = Wswz + ((colbase + c) * 2 + q) * 8;
#pragma unroll 4
    for (int ks = 0; ks < KS16; ++ks) {
      short8 afr[2];
      afr[0] = *(const short8*)(ap + ks * 16);
      afr[1] = *(const short8*)(ap + 32 * LDX + ks * 16);
      short8 bfr[NCT];
#pragma unroll
      for (int ct = 0; ct < NCT; ++ct)
        bfr[ct] = *(const short8*)(bp + (size_t)ks * (M * 16) + ct * 32 * 16);
#pragma unroll
      for (int rt = 0; rt < 2; ++rt)
#pragma unroll
        for (int ct = 0; ct < NCT; ++ct)
          acc[rt][ct] = __builtin_amdgcn_mfma_f32_32x32x16_bf16(
              afr[rt], bfr[ct], acc[rt][ct], 0, 0, 0);
    }
    // pack h to bf16x2 pairs; acc dies here. C/D row=(r&3)+8*(r>>2)+4q.
#pragma unroll
    for (int rt = 0; rt < 2; ++rt)
#pragma unroll
      for (int ct = 0; ct < NCT; ++ct)
#pragma unroll
        for (int tp = 0; tp < 2; ++tp) {
          Ppk[ct][rt * 2 + tp][0] = packbf2(acc[rt][ct][8 * tp + 0], acc[rt][ct][8 * tp + 1]);
          Ppk[ct][rt * 2 + tp][1] = packbf2(acc[rt][ct][8 * tp + 2], acc[rt][ct][8 * tp + 3]);
          Ppk[ct][rt * 2 + tp][2] = packbf2(acc[rt][ct][8 * tp + 4], acc[rt][ct][8 * tp + 5]);
          Ppk[ct][rt * 2 + tp][3] = packbf2(acc[rt][ct][8 * tp + 6], acc[rt][ct][8 * tp + 7]);
        }
  }

  // ---- softmax: P rows in 32x32 A-frag regs; row i = rt*32 + c;
  //      k node = tt*16+q*8+j. Reads only sE (ready since bar1) — same
  //      unfenced region as phase1, so VALU can hide under MFMA. ----
  const float* lsrow = sE + hu * LDE;
  const float* ldrow = sE + (8 + hu) * LDE;
  short8 pfr[2][4];
#pragma unroll
  for (int rt = 0; rt < 2; ++rt) {
    const float ldi = ldrow[rt * 32 + c];
    float pe_[4][8];
    float rsum = 0.f;
#pragma unroll
    for (int tt = 0; tt < 4; ++tt) {
      float4 v0 = *(const float4*)(lsrow + tt * 16 + q * 8);
      float4 v1 = *(const float4*)(lsrow + tt * 16 + q * 8 + 4);
      float ls8[8] = {v0.x, v0.y, v0.z, v0.w, v1.x, v1.y, v1.z, v1.w};
#pragma unroll
      for (int jj = 0; jj < 8; ++jj) {
        float tv = ldi + ls8[jj];
        float e = exp2_hw(fmaxf(tv, 0.2f * tv));  // inputs pre-scaled by log2e
        pe_[tt][jj] = e;
        rsum += e;
      }
    }
    rsum += __shfl_xor(rsum, 32, 64);
    const float ri = rcp_hw(rsum);
#pragma unroll
    for (int tt = 0; tt < 4; ++tt) {
      union { uint32 d[4]; short8 s; } w;
#pragma unroll
      for (int jp = 0; jp < 4; ++jp)
        w.d[jp] = packbf2(pe_[tt][2 * jp] * ri, pe_[tt][2 * jp + 1] * ri);
      pfr[rt][tt] = w.s;
    }
  }

  __syncthreads();  // bar2: every wave's sX reads (E + phase1) are complete

  // ---- per-ct: h C/D -> B-frag (one permlane32_swap per dword pair),
  //      O = P@h + bias (folded into acc init), store to sX ----
#pragma unroll
  for (int ct = 0; ct < NCT; ++ct) {
    short8 hfr[4];
#pragma unroll
    for (int tt = 0; tt < 4; ++tt) {
      uint32 U0 = Ppk[ct][tt][0], U1 = Ppk[ct][tt][1];
      uint32 V0 = Ppk[ct][tt][2], V1 = Ppk[ct][tt][3];
      uint32 d0, d1, d2, d3;
      lane32_swap(U0, V0, q, d0, d2);  // d0: own-U/partner-V; d2: partner-U/own-V
      lane32_swap(U1, V1, q, d1, d3);
      union { uint32 d[4]; short8 s; } u;
      u.d[0] = d0; u.d[1] = d1; u.d[2] = d2; u.d[3] = d3;
      hfr[tt] = u.s;
    }
    const float bv = bias[colbase + ct * 32 + c];
    float16v oacc[2];
    oacc[0] = (float16v)bv;  // bias pre-loaded into the accumulator (exact:
    oacc[1] = (float16v)bv;  // all 16 C/D elems of a lane share column c)
#pragma unroll
    for (int tt = 0; tt < 4; ++tt) {
      oacc[0] = __builtin_amdgcn_mfma_f32_32x32x16_bf16(pfr[0][tt], hfr[tt], oacc[0], 0, 0, 0);
      oacc[1] = __builtin_amdgcn_mfma_f32_32x32x16_bf16(pfr[1][tt], hfr[tt], oacc[1], 0, 0, 0);
    }
#pragma unroll
    for (int rt = 0; rt < 2; ++rt)
#pragma unroll
      for (int r = 0; r < 16; ++r) {
        float val = oacc[rt][r];
        int row = rt * 32 + (r & 3) + 8 * (r >> 2) + 4 * q;
        if constexpr (LAST)
          ((float*)sX)[row * 260 + colbase + ct * 32 + c] = val;
        else
          sX[row * LDX + colbase + ct * 32 + c] = f2b1(val);
      }
  }
  __syncthreads();  // bar3: x' complete before next layer / mean
}

__global__ __launch_bounds__(THREADS, 4) void gat3_mfma(
    const float* __restrict__ xs, const float* __restrict__ pe,
    const bf16* __restrict__ W1s, const bf16* __restrict__ WE1,
    const float* __restrict__ b1, const bf16* __restrict__ W2s,
    const bf16* __restrict__ WE2, const float* __restrict__ b2,
    const bf16* __restrict__ W3s, const bf16* __restrict__ WE3,
    const float* __restrict__ b3, float* __restrict__ out) {
  extern __shared__ char smem[];
  bf16* sX = (bf16*)smem;              // 64*520*2 = 66560 B
  float* sE = (float*)(smem + 66560);  // 16*68*4 = 4352 B -> total 70912

  const int t = threadIdx.x;
  const int blk = blockIdx.x;  // bs*R = 2048 graphs
  const int bidx = blk >> 8;   // batch index (R=256)

  // x0 = concat(xs, broadcast pos_enc) -> [64][32] bf16, stride LDX
  for (int idx = t; idx < 64 * 32; idx += THREADS) {
    int n = idx >> 5, f = idx & 31;
    float v = (f == 0) ? xs[blk * 64 + n] : pe[(bidx * 64 + n) * 31 + (f - 1)];
    sX[n * LDX + f] = f2b(v);
  }
  __syncthreads();

  gat_layer<32, 512, 64, false>(t, W1s, WE1, b1, sX, sE);
  gat_layer<512, 512, 64, false>(t, W2s, WE2, b2, sX, sE);
  gat_layer<512, 256, 32, true>(t, W3s, WE3, b3, sX, sE);

  // mean over 64 nodes -> [256]; split across both wave-halves:
  // waves 4-7 sum rows 32..63 into sE (free after last layer), bar,
  // waves 0-3 sum rows 0..31 and combine.
  const float* xf = (const float*)sX;
  float* sPart = sE;  // 256 floats, fits in sE region
  if (t >= 256) {
    float s = 0.f;
#pragma unroll 8
    for (int i = 32; i < 64; ++i) s += xf[i * 260 + (t - 256)];
    sPart[t - 256] = s;
  }
  __syncthreads();
  if (t < 256) {
    float s = 0.f;
#pragma unroll 8
    for (int i = 0; i < 32; ++i) s += xf[i * 260 + t];
    out[blk * 256 + t] = (s + sPart[t]) * 0.015625f;
  }
}

extern "C" void kernel_launch(void* const* d_in, const int* in_sizes, int n_in,
                              void* d_out, int out_size, void* d_ws, size_t ws_size,
                              hipStream_t stream) {
  const float* xs = (const float*)d_in[0];
  const float* pe = (const float*)d_in[1];
  const float* W1 = (const float*)d_in[2];
  const float* as1 = (const float*)d_in[3];
  const float* ad1 = (const float*)d_in[4];
  const float* b1 = (const float*)d_in[5];
  const float* W2 = (const float*)d_in[6];
  const float* as2 = (const float*)d_in[7];
  const float* ad2 = (const float*)d_in[8];
  const float* b2 = (const float*)d_in[9];
  const float* W3 = (const float*)d_in[10];
  const float* as3 = (const float*)d_in[11];
  const float* ad3 = (const float*)d_in[12];
  const float* b3 = (const float*)d_in[13];

  bf16* Wall = (bf16*)d_ws;          // 409600 elems
  bf16* WEall = Wall + 409600;       // 16896 elems (total 852992 B)
  bf16* W1s = Wall;
  bf16* W2s = Wall + 16384;
  bf16* W3s = Wall + 278528;
  bf16* WE1 = WEall;
  bf16* WE2 = WEall + 512;
  bf16* WE3 = WEall + 8704;

  // parts A (400 blocks, float4) + B (264 blocks) fused
  prep_all<<<dim3(664), dim3(256), 0, stream>>>(
      W1, W2, W3, as1, ad1, as2, ad2, as3, ad3, Wall, WEall);

  // one-time: raise dynamic-smem cap (host-side; keep out of steady-state)
  static bool smem_inited = false;
  if (!smem_inited) {
    (void)hipFuncSetAttribute((const void*)gat3_mfma,
                              hipFuncAttributeMaxDynamicSharedMemorySize,
                              70912);
    smem_inited = true;
  }
  gat3_mfma<<<dim3(2048), dim3(THREADS), 70912, stream>>>(
      xs, pe, W1s, WE1, b1, W2s, WE2, b2, W3s, WE3, b3, (float*)d_out);
}